// Round 1
// baseline (577.206 us; speedup 1.0000x reference)
//
#include <hip/hip_runtime.h>
#include <hip/hip_bf16.h>
#include <cstdint>
#include <cstddef>

// Fused: h = x @ W^T + b ; per-row instance-norm over 2048 feats ; out = (normed+y)*y
// B=32768, IN=128, OUT=2048, fp32 in/out. Strategy: bf16 MFMA GEMM with
// register-resident h (never hits memory), block owns 16 rows x all 2048 cols
// so the norm reduction is intra-block. HBM-bound on y+out (~537 MB).

#define IN_DIM  128
#define OUT_DIM 2048
#define ROWS    16      // rows per block
#define EPS     1e-5f

typedef short  short8  __attribute__((ext_vector_type(8)));   // 8 bf16 bits
typedef float  floatx4 __attribute__((ext_vector_type(4)));

__device__ __forceinline__ unsigned short f2bf(float f) {
    union { float f; unsigned int u; } v; v.f = f;
    unsigned int u = v.u;
    u += 0x7fffu + ((u >> 16) & 1u);   // round-to-nearest-even
    return (unsigned short)(u >> 16);
}

// Kernel 1: convert linear_w fp32 -> bf16 (bit pattern in ushort) into ws.
__global__ void convert_w_kernel(const float* __restrict__ w,
                                 unsigned short* __restrict__ wbf, int n) {
    int i = (blockIdx.x * blockDim.x + threadIdx.x) * 4;
    if (i < n) {
        float4 v = *(const float4*)(w + i);
        ushort4 o;
        o.x = f2bf(v.x); o.y = f2bf(v.y); o.z = f2bf(v.z); o.w = f2bf(v.w);
        *(ushort4*)(wbf + i) = o;
    }
}

// Main fused kernel: 512 threads = 8 waves. Wave w owns cols [w*256, w*256+256).
// Block owns rows [blockIdx.x*16, +16).
__global__ __launch_bounds__(512)
void fused_linear_norm_kernel(const float* __restrict__ x,
                              const float* __restrict__ y,
                              const unsigned short* __restrict__ wbf,
                              const float* __restrict__ lb,
                              const float* __restrict__ nw,
                              const float* __restrict__ nb,
                              float* __restrict__ out) {
    const int tid  = threadIdx.x;
    const int wave = tid >> 6;        // 0..7
    const int lane = tid & 63;
    const int l15  = lane & 15;
    const int quad = lane >> 4;       // 0..3
    const int row0 = blockIdx.x * ROWS;

    // ---- A fragments: x rows, fp32 -> bf16 on load. 4 K-steps of 32. ----
    // A layout: lane holds A[m=lane&15][k = quad*8 + j], j=0..7
    short8 afrag[4];
    {
        const float* xr = x + (size_t)(row0 + l15) * IN_DIM + quad * 8;
        #pragma unroll
        for (int s = 0; s < 4; ++s) {
            float4 p0 = *(const float4*)(xr + s * 32);
            float4 p1 = *(const float4*)(xr + s * 32 + 4);
            short8 a;
            a[0] = (short)f2bf(p0.x); a[1] = (short)f2bf(p0.y);
            a[2] = (short)f2bf(p0.z); a[3] = (short)f2bf(p0.w);
            a[4] = (short)f2bf(p1.x); a[5] = (short)f2bf(p1.y);
            a[6] = (short)f2bf(p1.z); a[7] = (short)f2bf(p1.w);
            afrag[s] = a;
        }
    }

    // ---- MFMA main: 16 tiles of 16x16, K=128 in 4 steps ----
    // B layout: lane holds B[k=quad*8+j][n=lane&15]; B[k][n] = W[n][k], W row-major
    // -> 16 contiguous bytes from bf16 W row (c0+t*16+l15) at k-offset.
    floatx4 acc[16];
    const int c0 = wave * 256;
    #pragma unroll
    for (int t = 0; t < 16; ++t) {
        acc[t] = (floatx4){0.f, 0.f, 0.f, 0.f};
        const unsigned short* wp = wbf + (size_t)(c0 + t * 16 + l15) * IN_DIM + quad * 8;
        #pragma unroll
        for (int s = 0; s < 4; ++s) {
            short8 b = *(const short8*)(wp + s * 32);
            acc[t] = __builtin_amdgcn_mfma_f32_16x16x32_bf16(afrag[s], b, acc[t], 0, 0, 0);
        }
    }

    // ---- bias add + per-row partial sums ----
    // C/D layout: col = c0 + t*16 + (lane&15); row = quad*4 + r
    float s1[4] = {0.f, 0.f, 0.f, 0.f};
    float s2[4] = {0.f, 0.f, 0.f, 0.f};
    #pragma unroll
    for (int t = 0; t < 16; ++t) {
        int col = c0 + t * 16 + l15;
        float bv = lb[col];
        #pragma unroll
        for (int r = 0; r < 4; ++r) {
            float h = acc[t][r] + bv;
            acc[t][r] = h;
            s1[r] += h;
            s2[r] += h * h;
        }
    }

    // butterfly over the 16-lane quad (quads own disjoint rows)
    #pragma unroll
    for (int off = 1; off < 16; off <<= 1) {
        #pragma unroll
        for (int r = 0; r < 4; ++r) {
            s1[r] += __shfl_xor(s1[r], off);
            s2[r] += __shfl_xor(s2[r], off);
        }
    }

    __shared__ float red1[8][ROWS];
    __shared__ float red2[8][ROWS];
    __shared__ float smean[ROWS], sinv[ROWS];
    if (l15 == 0) {
        #pragma unroll
        for (int r = 0; r < 4; ++r) {
            red1[wave][quad * 4 + r] = s1[r];
            red2[wave][quad * 4 + r] = s2[r];
        }
    }
    __syncthreads();
    if (tid < ROWS) {
        float t1 = 0.f, t2 = 0.f;
        #pragma unroll
        for (int w = 0; w < 8; ++w) { t1 += red1[w][tid]; t2 += red2[w][tid]; }
        float mean = t1 * (1.0f / OUT_DIM);
        float var  = t2 * (1.0f / OUT_DIM) - mean * mean;
        smean[tid] = mean;
        sinv[tid]  = rsqrtf(var + EPS);
    }
    __syncthreads();

    float mean[4], inv[4];
    #pragma unroll
    for (int r = 0; r < 4; ++r) {
        mean[r] = smean[quad * 4 + r];
        inv[r]  = sinv[quad * 4 + r];
    }

    // ---- epilogue: normalize, fuse y, stream out ----
    #pragma unroll
    for (int t = 0; t < 16; ++t) {
        int col = c0 + t * 16 + l15;
        float gw = nw[col];
        float gb = nb[col];
        #pragma unroll
        for (int r = 0; r < 4; ++r) {
            size_t idx = (size_t)(row0 + quad * 4 + r) * OUT_DIM + col;
            float yv = y[idx];
            float normed = (acc[t][r] - mean[r]) * inv[r] * gw + gb;
            out[idx] = (normed + yv) * yv;
        }
    }
}

extern "C" void kernel_launch(void* const* d_in, const int* in_sizes, int n_in,
                              void* d_out, int out_size, void* d_ws, size_t ws_size,
                              hipStream_t stream) {
    const float* x  = (const float*)d_in[0];
    const float* y  = (const float*)d_in[1];
    const float* lw = (const float*)d_in[2];
    const float* lb = (const float*)d_in[3];
    const float* nw = (const float*)d_in[4];
    const float* nb = (const float*)d_in[5];
    float* out = (float*)d_out;
    unsigned short* wbf = (unsigned short*)d_ws;   // 2048*128*2B = 512 KB

    const int wn = OUT_DIM * IN_DIM;               // 262144
    convert_w_kernel<<<wn / 4 / 256, 256, 0, stream>>>(lw, wbf, wn);

    const int nblocks = 32768 / ROWS;              // 2048
    fused_linear_norm_kernel<<<nblocks, 512, 0, stream>>>(x, y, wbf, lb, nw, nb, out);
}

// Round 2
// 549.196 us; speedup vs baseline: 1.0510x; 1.0510x over previous
//
#include <hip/hip_runtime.h>
#include <hip/hip_bf16.h>
#include <cstdint>
#include <cstddef>

// Fused: h = x @ W^T + b ; per-row instance-norm over 2048 feats ; out = (normed+y)*y
// B=32768, IN=128, OUT=2048, fp32 in/out.
// R2: epilogue transposes MFMA C-layout -> row-major via per-wave LDS slab so the
// y-read / out-write stream is float4-vectorized (R1 was scalar-dword, latency-bound
// at 1.6 TB/s).

#define IN_DIM  128
#define OUT_DIM 2048
#define ROWS    16      // rows per block
#define EPS     1e-5f

typedef short  short8  __attribute__((ext_vector_type(8)));   // 8 bf16 bits
typedef float  floatx4 __attribute__((ext_vector_type(4)));

__device__ __forceinline__ unsigned short f2bf(float f) {
    union { float f; unsigned int u; } v; v.f = f;
    unsigned int u = v.u;
    u += 0x7fffu + ((u >> 16) & 1u);   // round-to-nearest-even
    return (unsigned short)(u >> 16);
}

// Kernel 1: convert linear_w fp32 -> bf16 (bit pattern in ushort) into ws.
__global__ void convert_w_kernel(const float* __restrict__ w,
                                 unsigned short* __restrict__ wbf, int n) {
    int i = (blockIdx.x * blockDim.x + threadIdx.x) * 4;
    if (i < n) {
        float4 v = *(const float4*)(w + i);
        ushort4 o;
        o.x = f2bf(v.x); o.y = f2bf(v.y); o.z = f2bf(v.z); o.w = f2bf(v.w);
        *(ushort4*)(wbf + i) = o;
    }
}

// Main fused kernel: 512 threads = 8 waves. Wave w owns cols [w*256, w*256+256).
// Block owns rows [blockIdx.x*16, +16).
__global__ __launch_bounds__(512)
void fused_linear_norm_kernel(const float* __restrict__ x,
                              const float* __restrict__ y,
                              const unsigned short* __restrict__ wbf,
                              const float* __restrict__ lb,
                              const float* __restrict__ nw,
                              const float* __restrict__ nb,
                              float* __restrict__ out) {
    const int tid  = threadIdx.x;
    const int wave = tid >> 6;        // 0..7
    const int lane = tid & 63;
    const int l15  = lane & 15;
    const int quad = lane >> 4;       // 0..3
    const int row0 = blockIdx.x * ROWS;

    // ---- A fragments: x rows, fp32 -> bf16 on load. 4 K-steps of 32. ----
    // A layout: lane holds A[m=lane&15][k = quad*8 + j], j=0..7
    short8 afrag[4];
    {
        const float* xr = x + (size_t)(row0 + l15) * IN_DIM + quad * 8;
        #pragma unroll
        for (int s = 0; s < 4; ++s) {
            float4 p0 = *(const float4*)(xr + s * 32);
            float4 p1 = *(const float4*)(xr + s * 32 + 4);
            short8 a;
            a[0] = (short)f2bf(p0.x); a[1] = (short)f2bf(p0.y);
            a[2] = (short)f2bf(p0.z); a[3] = (short)f2bf(p0.w);
            a[4] = (short)f2bf(p1.x); a[5] = (short)f2bf(p1.y);
            a[6] = (short)f2bf(p1.z); a[7] = (short)f2bf(p1.w);
            afrag[s] = a;
        }
    }

    // ---- MFMA main: 16 tiles of 16x16, K=128 in 4 steps ----
    // B layout: lane holds B[k=quad*8+j][n=lane&15]; B[k][n] = W[n][k], W row-major
    floatx4 acc[16];
    const int c0 = wave * 256;
    #pragma unroll
    for (int t = 0; t < 16; ++t) {
        acc[t] = (floatx4){0.f, 0.f, 0.f, 0.f};
        const unsigned short* wp = wbf + (size_t)(c0 + t * 16 + l15) * IN_DIM + quad * 8;
        #pragma unroll
        for (int s = 0; s < 4; ++s) {
            short8 b = *(const short8*)(wp + s * 32);
            acc[t] = __builtin_amdgcn_mfma_f32_16x16x32_bf16(afrag[s], b, acc[t], 0, 0, 0);
        }
    }

    // ---- bias add + per-row partial sums ----
    // C/D layout: col = c0 + t*16 + (lane&15); row = quad*4 + r
    float s1[4] = {0.f, 0.f, 0.f, 0.f};
    float s2[4] = {0.f, 0.f, 0.f, 0.f};
    #pragma unroll
    for (int t = 0; t < 16; ++t) {
        int col = c0 + t * 16 + l15;
        float bv = lb[col];
        #pragma unroll
        for (int r = 0; r < 4; ++r) {
            float h = acc[t][r] + bv;
            acc[t][r] = h;
            s1[r] += h;
            s2[r] += h * h;
        }
    }

    // butterfly over the 16-lane quad (quads own disjoint rows)
    #pragma unroll
    for (int off = 1; off < 16; off <<= 1) {
        #pragma unroll
        for (int r = 0; r < 4; ++r) {
            s1[r] += __shfl_xor(s1[r], off);
            s2[r] += __shfl_xor(s2[r], off);
        }
    }

    __shared__ float red1[8][ROWS];
    __shared__ float red2[8][ROWS];
    __shared__ float smean[ROWS], sinv[ROWS];
    if (l15 == 0) {
        #pragma unroll
        for (int r = 0; r < 4; ++r) {
            red1[wave][quad * 4 + r] = s1[r];
            red2[wave][quad * 4 + r] = s2[r];
        }
    }
    __syncthreads();
    if (tid < ROWS) {
        float t1 = 0.f, t2 = 0.f;
        #pragma unroll
        for (int w = 0; w < 8; ++w) { t1 += red1[w][tid]; t2 += red2[w][tid]; }
        float mean = t1 * (1.0f / OUT_DIM);
        float var  = t2 * (1.0f / OUT_DIM) - mean * mean;
        smean[tid] = mean;
        sinv[tid]  = rsqrtf(var + EPS);
    }
    __syncthreads();

    float mean[4], inv[4];
    #pragma unroll
    for (int r = 0; r < 4; ++r) {
        mean[r] = smean[quad * 4 + r];
        inv[r]  = sinv[quad * 4 + r];
    }

    // ---- epilogue: normalize -> per-wave LDS transpose -> vectorized y-fuse ----
    // Per chunk (64 cols): write normed in C-layout (ds_write_b32, 2-way bank
    // aliasing = free w/ 68-float row pitch), read back row-major as float4
    // (conflict-free), then float4 y-load / out-store: 4 rows x 256 B contiguous
    // segments per instruction, 16 B/lane in flight.
    __shared__ float stage[8][ROWS][68];   // 34.8 KB
    #pragma unroll
    for (int c = 0; c < 4; ++c) {
        #pragma unroll
        for (int tl = 0; tl < 4; ++tl) {
            const int t   = c * 4 + tl;
            const int col = c0 + t * 16 + l15;
            const float gw = nw[col];
            const float gb = nb[col];
            #pragma unroll
            for (int r = 0; r < 4; ++r) {
                const float normed = (acc[t][r] - mean[r]) * inv[r] * gw + gb;
                stage[wave][quad * 4 + r][tl * 16 + l15] = normed;
            }
        }
        // intra-wave LDS RAW: DS pipe is in-order per wave; waitcnt + mem clobber
        // keeps the compiler from sinking reads above writes.
        __asm__ volatile("s_waitcnt lgkmcnt(0)" ::: "memory");
        #pragma unroll
        for (int i = 0; i < 4; ++i) {
            const int rl = i * 4 + quad;                 // local row
            const float4 v = *(const float4*)&stage[wave][rl][l15 * 4];
            const size_t idx = (size_t)(row0 + rl) * OUT_DIM + (c0 + c * 64 + l15 * 4);
            const float4 yv = *(const float4*)(y + idx);
            float4 o;
            o.x = (v.x + yv.x) * yv.x;
            o.y = (v.y + yv.y) * yv.y;
            o.z = (v.z + yv.z) * yv.z;
            o.w = (v.w + yv.w) * yv.w;
            *(float4*)(out + idx) = o;
        }
    }
}

extern "C" void kernel_launch(void* const* d_in, const int* in_sizes, int n_in,
                              void* d_out, int out_size, void* d_ws, size_t ws_size,
                              hipStream_t stream) {
    const float* x  = (const float*)d_in[0];
    const float* y  = (const float*)d_in[1];
    const float* lw = (const float*)d_in[2];
    const float* lb = (const float*)d_in[3];
    const float* nw = (const float*)d_in[4];
    const float* nb = (const float*)d_in[5];
    float* out = (float*)d_out;
    unsigned short* wbf = (unsigned short*)d_ws;   // 2048*128*2B = 512 KB

    const int wn = OUT_DIM * IN_DIM;               // 262144
    convert_w_kernel<<<wn / 4 / 256, 256, 0, stream>>>(lw, wbf, wn);

    const int nblocks = 32768 / ROWS;              // 2048
    fused_linear_norm_kernel<<<nblocks, 512, 0, stream>>>(x, y, wbf, lb, nw, nb, out);
}